// Round 6
// baseline (216.800 us; speedup 1.0000x reference)
//
#include <hip/hip_runtime.h>
#include <hip/hip_bf16.h>

#define INC   256
#define HEADS 4
#define OUTC  64
#define NEG_SLOPE 0.2f

typedef __attribute__((ext_vector_type(8))) short  fragA;  // 8 bf16 in 4 VGPRs
typedef __attribute__((ext_vector_type(4))) float  f32x4;

__device__ __forceinline__ float bf2f(unsigned short u) {
    union { unsigned int i; float f; } v; v.i = ((unsigned int)u) << 16; return v.f;
}
__device__ __forceinline__ unsigned short f2bf(float x) {
    __hip_bfloat16 b = __float2bfloat16(x);
    return *reinterpret_cast<unsigned short*>(&b);
}

// ---------------- Wt = bf16(W^T) [256 n][256 k]; also zero counts ----------------
__global__ __launch_bounds__(256) void wt_zero_kernel(const float* __restrict__ W,
                                                      unsigned short* __restrict__ Wt,
                                                      int* __restrict__ counts, int n)
{
    int idx = blockIdx.x * 256 + threadIdx.x;   // 0..65535
    int k = idx >> 8, c = idx & 255;
    Wt[c * 256 + k] = f2bf(W[k * 256 + c]);
    if (idx < n) counts[idx] = 0;
}

// ---------------- GEMM + att: h2 = bf16(x @ W); a_src/a_dst from f32 acc ----------------
// grid (M/64): block = 64 rows x 256 cols. 4 waves; wave w owns cols w*64.. (== head w).
// B slice lives in registers (32 fragA/lane); A tile staged once (full K) in LDS.
__global__ __launch_bounds__(256, 2) void gemm_att_mfma(
    const float* __restrict__ A,            // [M,256] f32
    const unsigned short* __restrict__ Wt,  // [256 n][256 k] bf16
    const float* __restrict__ att_src,      // [4,64]
    const float* __restrict__ att_dst,      // [4,64]
    unsigned short* __restrict__ H2,        // [M,256] bf16
    float* __restrict__ a_srcO,             // [M,4]
    float* __restrict__ a_dstO,             // [M,4]
    int M)
{
    __shared__ __align__(16) unsigned short As[64 * 256];   // 32 KB, swizzled
    const int tid  = threadIdx.x;
    const int lane = tid & 63;
    const int wave = tid >> 6;          // col slice == head
    const int row0 = blockIdx.x * 64;
    const int g   = lane >> 4;
    const int r16 = lane & 15;

    // preload B fragments: b[nn][kk] for col = wave*64 + nn*16 + r16
    fragA b[4][8];
    {
        const unsigned short* wp = Wt + (size_t)(wave * 64) * 256;
        #pragma unroll
        for (int nn = 0; nn < 4; ++nn)
            #pragma unroll
            for (int kk = 0; kk < 8; ++kk)
                b[nn][kk] = *(const fragA*)(wp + (size_t)(nn * 16 + r16) * 256 + kk * 32 + g * 8);
    }

    // stage A tile: 64 rows x 256 k, f32 -> bf16, swizzled [row][k]
    #pragma unroll
    for (int i = 0; i < 16; ++i) {
        int f   = i * 256 + tid;        // float4-quad index
        int row = f >> 6;               // 0..63
        int q   = f & 63;               // quad within row
        int gr  = row0 + row;
        float4 v = (gr < M) ? *(const float4*)(A + (size_t)gr * INC + q * 4)
                            : make_float4(0.f, 0.f, 0.f, 0.f);
        ushort4 u;
        u.x = f2bf(v.x); u.y = f2bf(v.y); u.z = f2bf(v.z); u.w = f2bf(v.w);
        int byte = (row << 9) + (q << 3);
        byte ^= (row & 7) << 4;
        *(ushort4*)((char*)As + byte) = u;
    }
    __syncthreads();

    f32x4 acc[4][4] = {};
    #pragma unroll
    for (int kk = 0; kk < 8; ++kk) {
        fragA a[4];
        #pragma unroll
        for (int m = 0; m < 4; ++m) {
            int row  = m * 16 + r16;
            int byte = (row << 9) + ((kk * 32 + g * 8) << 1);
            byte ^= (row & 7) << 4;
            a[m] = *(const fragA*)((const char*)As + byte);
        }
        #pragma unroll
        for (int m = 0; m < 4; ++m)
            #pragma unroll
            for (int nn = 0; nn < 4; ++nn)
                acc[m][nn] = __builtin_amdgcn_mfma_f32_16x16x32_bf16(
                    a[m], b[nn][kk], acc[m][nn], 0, 0, 0);
    }

    // h2 write. C/D layout: col = lane&15, row = (lane>>4)*4 + reg
    #pragma unroll
    for (int m = 0; m < 4; ++m) {
        #pragma unroll
        for (int nn = 0; nn < 4; ++nn) {
            int gcol = wave * 64 + nn * 16 + r16;
            #pragma unroll
            for (int r = 0; r < 4; ++r) {
                int grow = row0 + m * 16 + g * 4 + r;
                if (grow < M)
                    H2[(size_t)grow * (HEADS * OUTC) + gcol] = f2bf(acc[m][nn][r]);
            }
        }
    }

    // att partials: this wave covers exactly head `wave`'s 64 channels.
    {
        float as_att[4], ad_att[4];
        #pragma unroll
        for (int nn = 0; nn < 4; ++nn) {
            as_att[nn] = att_src[wave * 64 + nn * 16 + r16];
            ad_att[nn] = att_dst[wave * 64 + nn * 16 + r16];
        }
        float sv[4][4], dv[4][4];
        #pragma unroll
        for (int m = 0; m < 4; ++m)
            #pragma unroll
            for (int r = 0; r < 4; ++r) {
                float s = 0.f, d = 0.f;
                #pragma unroll
                for (int nn = 0; nn < 4; ++nn) {
                    s = fmaf(acc[m][nn][r], as_att[nn], s);
                    d = fmaf(acc[m][nn][r], ad_att[nn], d);
                }
                sv[m][r] = s; dv[m][r] = d;
            }
        // reduce over the 16 lanes (r16) of each g-group
        #pragma unroll
        for (int off = 1; off < 16; off <<= 1) {
            #pragma unroll
            for (int m = 0; m < 4; ++m)
                #pragma unroll
                for (int r = 0; r < 4; ++r) {
                    sv[m][r] += __shfl_xor(sv[m][r], off, 64);
                    dv[m][r] += __shfl_xor(dv[m][r], off, 64);
                }
        }
        // lane r16 = m*4+r writes row = row0 + m*16 + g*4 + r
        #pragma unroll
        for (int m = 0; m < 4; ++m)
            #pragma unroll
            for (int r = 0; r < 4; ++r) {
                if (r16 == m * 4 + r) {
                    int grow = row0 + m * 16 + g * 4 + r;
                    if (grow < M) {
                        a_srcO[(size_t)grow * HEADS + wave] = sv[m][r];
                        a_dstO[(size_t)grow * HEADS + wave] = dv[m][r];
                    }
                }
            }
    }
}

// ---------------- CSR build ----------------
__global__ void hist_kernel(const int* __restrict__ dst, int* __restrict__ counts, int E)
{
    int e = blockIdx.x * blockDim.x + threadIdx.x;
    if (e < E) atomicAdd(&counts[dst[e]], 1);
}

__global__ __launch_bounds__(256) void scan1_kernel(const int* __restrict__ counts,
                                                    int* __restrict__ local,
                                                    int* __restrict__ bsums, int n)
{
    __shared__ int tmp[256];
    int t = threadIdx.x;
    int i = blockIdx.x * 256 + t;
    int v = (i < n) ? counts[i] : 0;
    tmp[t] = v;
    __syncthreads();
    for (int off = 1; off < 256; off <<= 1) {
        int x = (t >= off) ? tmp[t - off] : 0;
        __syncthreads();
        tmp[t] += x;
        __syncthreads();
    }
    if (i < n) local[i] = tmp[t] - v;
    if (t == 255) bsums[blockIdx.x] = tmp[255];
}

__global__ __launch_bounds__(256) void scan3b_kernel(const int* __restrict__ local,
                                                     const int* __restrict__ bsums,
                                                     int* __restrict__ offsets,
                                                     int* __restrict__ cursor,
                                                     int n, int Etot)
{
    __shared__ int red[256];
    int t = threadIdx.x;
    int bid = blockIdx.x;
    int s = 0;
    for (int j = t; j < bid; j += 256) s += bsums[j];
    red[t] = s;
    __syncthreads();
    for (int off = 128; off > 0; off >>= 1) {
        if (t < off) red[t] += red[t + off];
        __syncthreads();
    }
    int base = red[0];
    int i = bid * 256 + t;
    if (i < n) {
        int o = local[i] + base;
        offsets[i] = o;
        cursor[i]  = o;
    }
    if (bid == 0 && t == 0) offsets[n] = Etot;
}

// ---------------- scatter + per-edge unnormalized alpha (head-major [4][E]) ----------------
__global__ void scatter_alpha_kernel(const int* __restrict__ src, const int* __restrict__ dst,
                                     const float* __restrict__ a_src,
                                     const float* __restrict__ a_dst,
                                     int* __restrict__ cursor,
                                     int* __restrict__ esrc,
                                     float* __restrict__ palpha, int E)
{
    int e = blockIdx.x * blockDim.x + threadIdx.x;
    if (e >= E) return;
    int s = src[e], d = dst[e];
    float4 as = *(const float4*)(a_src + (size_t)s * HEADS);
    float4 ad = *(const float4*)(a_dst + (size_t)d * HEADS);
    float4 p;
    float t;
    t = as.x + ad.x; t = t > 0.f ? t : NEG_SLOPE * t; p.x = __expf(t);
    t = as.y + ad.y; t = t > 0.f ? t : NEG_SLOPE * t; p.y = __expf(t);
    t = as.z + ad.z; t = t > 0.f ? t : NEG_SLOPE * t; p.z = __expf(t);
    t = as.w + ad.w; t = t > 0.f ? t : NEG_SLOPE * t; p.w = __expf(t);
    int pos = atomicAdd(&cursor[d], 1);
    esrc[pos] = s;
    palpha[pos]             = p.x;
    palpha[(size_t)E + pos] = p.y;
    palpha[2 * (size_t)E + pos] = p.z;
    palpha[3 * (size_t)E + pos] = p.w;
}

// ---------------- fused aggregation: wave per node; lane = head*16 + cg ----------------
__global__ __launch_bounds__(256) void fused_agg_kernel(
    const unsigned short* __restrict__ h2,      // [N,256] bf16
    const float* __restrict__ a_src,            // [N,4]
    const float* __restrict__ a_dst,            // [N,4]
    const int*   __restrict__ offsets,          // [N+1]
    const int*   __restrict__ esrc,             // [E]
    const float* __restrict__ palpha,           // [4][E]
    const float* __restrict__ bias,             // [64]
    float*       __restrict__ out,              // [N,64]
    int n, int E)
{
    int i    = (int)((blockIdx.x * blockDim.x + threadIdx.x) >> 6);
    int lane = threadIdx.x & 63;
    if (i >= n) return;
    const int h  = lane >> 4;
    const int cg = lane & 15;

    float acc0, acc1, acc2, acc3, l;
    {   // self-loop
        float as = a_src[(size_t)i * HEADS + h];
        float ad = a_dst[(size_t)i * HEADS + h];
        float e = as + ad; e = e > 0.f ? e : NEG_SLOPE * e;
        float p = __expf(e);
        ushort4 v = *(const ushort4*)(h2 + (size_t)i * 256 + lane * 4);
        l = p;
        acc0 = p * bf2f(v.x);
        acc1 = p * bf2f(v.y);
        acc2 = p * bf2f(v.z);
        acc3 = p * bf2f(v.w);
    }

    const float* pa = palpha + (size_t)h * E;
    int beg = offsets[i], end = offsets[i + 1];
    int j = beg;
    for (; j + 3 < end; j += 4) {
        int s0 = esrc[j];
        int s1 = esrc[j + 1];
        int s2 = esrc[j + 2];
        int s3 = esrc[j + 3];
        float p0 = pa[j];
        float p1 = pa[j + 1];
        float p2 = pa[j + 2];
        float p3 = pa[j + 3];
        ushort4 v0 = *(const ushort4*)(h2 + (size_t)s0 * 256 + lane * 4);
        ushort4 v1 = *(const ushort4*)(h2 + (size_t)s1 * 256 + lane * 4);
        ushort4 v2 = *(const ushort4*)(h2 + (size_t)s2 * 256 + lane * 4);
        ushort4 v3 = *(const ushort4*)(h2 + (size_t)s3 * 256 + lane * 4);
        l += (p0 + p1) + (p2 + p3);
        acc0 = fmaf(p0, bf2f(v0.x), acc0);
        acc1 = fmaf(p0, bf2f(v0.y), acc1);
        acc2 = fmaf(p0, bf2f(v0.z), acc2);
        acc3 = fmaf(p0, bf2f(v0.w), acc3);
        acc0 = fmaf(p1, bf2f(v1.x), acc0);
        acc1 = fmaf(p1, bf2f(v1.y), acc1);
        acc2 = fmaf(p1, bf2f(v1.z), acc2);
        acc3 = fmaf(p1, bf2f(v1.w), acc3);
        acc0 = fmaf(p2, bf2f(v2.x), acc0);
        acc1 = fmaf(p2, bf2f(v2.y), acc1);
        acc2 = fmaf(p2, bf2f(v2.z), acc2);
        acc3 = fmaf(p2, bf2f(v2.w), acc3);
        acc0 = fmaf(p3, bf2f(v3.x), acc0);
        acc1 = fmaf(p3, bf2f(v3.y), acc1);
        acc2 = fmaf(p3, bf2f(v3.z), acc2);
        acc3 = fmaf(p3, bf2f(v3.w), acc3);
    }
    for (; j < end; ++j) {
        int s0 = esrc[j];
        float p0 = pa[j];
        ushort4 v0 = *(const ushort4*)(h2 + (size_t)s0 * 256 + lane * 4);
        l += p0;
        acc0 = fmaf(p0, bf2f(v0.x), acc0);
        acc1 = fmaf(p0, bf2f(v0.y), acc1);
        acc2 = fmaf(p0, bf2f(v0.z), acc2);
        acc3 = fmaf(p0, bf2f(v0.w), acc3);
    }

    float inv = 1.f / (l + 1e-16f);
    float r0 = acc0 * inv, r1 = acc1 * inv, r2 = acc2 * inv, r3 = acc3 * inv;

    r0 += __shfl_xor(r0, 16, 64); r0 += __shfl_xor(r0, 32, 64);
    r1 += __shfl_xor(r1, 16, 64); r1 += __shfl_xor(r1, 32, 64);
    r2 += __shfl_xor(r2, 16, 64); r2 += __shfl_xor(r2, 32, 64);
    r3 += __shfl_xor(r3, 16, 64); r3 += __shfl_xor(r3, 32, 64);

    if (lane < 16) {
        float4 b4 = *(const float4*)(bias + cg * 4);
        float4 o;
        o.x = 0.25f * r0 + b4.x;
        o.y = 0.25f * r1 + b4.y;
        o.z = 0.25f * r2 + b4.z;
        o.w = 0.25f * r3 + b4.w;
        *(float4*)(out + (size_t)i * OUTC + cg * 4) = o;
    }
}

extern "C" void kernel_launch(void* const* d_in, const int* in_sizes, int n_in,
                              void* d_out, int out_size, void* d_ws, size_t ws_size,
                              hipStream_t stream)
{
    (void)n_in; (void)out_size; (void)ws_size;
    const float* x       = (const float*)d_in[0];
    const int*   edge    = (const int*)d_in[1];
    const float* W       = (const float*)d_in[2];
    const float* att_src = (const float*)d_in[3];
    const float* att_dst = (const float*)d_in[4];
    const float* bias    = (const float*)d_in[5];
    float* out = (float*)d_out;

    const int N = in_sizes[0] / INC;
    const int E = in_sizes[1] / 2;
    const int* srcA = edge;
    const int* dstA = edge + E;

    char* ws = (char*)d_ws;
    unsigned short* h2 = (unsigned short*)ws; ws += (size_t)N * (HEADS * OUTC) * sizeof(unsigned short);
    unsigned short* Wt = (unsigned short*)ws; ws += (size_t)256 * 256 * sizeof(unsigned short);
    float* a_src  = (float*)ws; ws += (size_t)N * HEADS * sizeof(float);
    float* a_dst  = (float*)ws; ws += (size_t)N * HEADS * sizeof(float);
    int* counts   = (int*)ws;   ws += (size_t)N * sizeof(int);
    int* offsets  = (int*)ws;   ws += (size_t)(N + 1) * sizeof(int) + 12;
    int* cursor   = (int*)ws;   ws += (size_t)N * sizeof(int);
    int* local    = (int*)ws;   ws += (size_t)N * sizeof(int);
    int* bsums    = (int*)ws;   ws += (size_t)1024 * sizeof(int);
    int* esrc     = (int*)ws;   ws += (size_t)E * sizeof(int);
    float* palpha = (float*)ws; ws += (size_t)4 * E * sizeof(float);

    const int nb = (N + 255) / 256;

    wt_zero_kernel<<<256, 256, 0, stream>>>(W, Wt, counts, N);

    hist_kernel<<<(E + 255) / 256, 256, 0, stream>>>(dstA, counts, E);

    gemm_att_mfma<<<(N + 63) / 64, 256, 0, stream>>>(x, Wt, att_src, att_dst,
                                                     h2, a_src, a_dst, N);

    scan1_kernel<<<nb, 256, 0, stream>>>(counts, local, bsums, N);
    scan3b_kernel<<<nb, 256, 0, stream>>>(local, bsums, offsets, cursor, N, E);

    scatter_alpha_kernel<<<(E + 255) / 256, 256, 0, stream>>>(srcA, dstA, a_src, a_dst,
                                                              cursor, esrc, palpha, E);

    fused_agg_kernel<<<(N + 3) / 4, 256, 0, stream>>>(h2, a_src, a_dst, offsets, esrc,
                                                      palpha, bias, out, N, E);
}

// Round 7
// 210.035 us; speedup vs baseline: 1.0322x; 1.0322x over previous
//
#include <hip/hip_runtime.h>
#include <hip/hip_bf16.h>

#define INC   256
#define HEADS 4
#define OUTC  64
#define NEG_SLOPE 0.2f

typedef __attribute__((ext_vector_type(8))) short  fragA;  // 8 bf16 in 4 VGPRs
typedef __attribute__((ext_vector_type(4))) float  f32x4;

__device__ __forceinline__ float bf2f(unsigned short u) {
    union { unsigned int i; float f; } v; v.i = ((unsigned int)u) << 16; return v.f;
}
__device__ __forceinline__ unsigned short f2bf(float x) {
    __hip_bfloat16 b = __float2bfloat16(x);
    return *reinterpret_cast<unsigned short*>(&b);
}

// ---------------- Wt = bf16(W^T) [256 n][256 k]; also zero counts ----------------
__global__ __launch_bounds__(256) void wt_zero_kernel(const float* __restrict__ W,
                                                      unsigned short* __restrict__ Wt,
                                                      int* __restrict__ counts, int n)
{
    int idx = blockIdx.x * 256 + threadIdx.x;   // 0..65535
    int k = idx >> 8, c = idx & 255;
    Wt[c * 256 + k] = f2bf(W[k * 256 + c]);
    if (idx < n) counts[idx] = 0;
}

// ---------------- GEMM + att: h2 = bf16(x @ W); a_src/a_dst from f32 acc ----------------
__global__ __launch_bounds__(256, 2) void gemm_att_mfma(
    const float* __restrict__ A,            // [M,256] f32
    const unsigned short* __restrict__ Wt,  // [256 n][256 k] bf16
    const float* __restrict__ att_src,      // [4,64]
    const float* __restrict__ att_dst,      // [4,64]
    unsigned short* __restrict__ H2,        // [M,256] bf16
    float* __restrict__ a_srcO,             // [M,4]
    float* __restrict__ a_dstO,             // [M,4]
    int M)
{
    __shared__ __align__(16) unsigned short As[64 * 256];   // 32 KB, swizzled
    const int tid  = threadIdx.x;
    const int lane = tid & 63;
    const int wave = tid >> 6;          // col slice == head
    const int row0 = blockIdx.x * 64;
    const int g   = lane >> 4;
    const int r16 = lane & 15;

    fragA b[4][8];
    {
        const unsigned short* wp = Wt + (size_t)(wave * 64) * 256;
        #pragma unroll
        for (int nn = 0; nn < 4; ++nn)
            #pragma unroll
            for (int kk = 0; kk < 8; ++kk)
                b[nn][kk] = *(const fragA*)(wp + (size_t)(nn * 16 + r16) * 256 + kk * 32 + g * 8);
    }

    #pragma unroll
    for (int i = 0; i < 16; ++i) {
        int f   = i * 256 + tid;
        int row = f >> 6;
        int q   = f & 63;
        int gr  = row0 + row;
        float4 v = (gr < M) ? *(const float4*)(A + (size_t)gr * INC + q * 4)
                            : make_float4(0.f, 0.f, 0.f, 0.f);
        ushort4 u;
        u.x = f2bf(v.x); u.y = f2bf(v.y); u.z = f2bf(v.z); u.w = f2bf(v.w);
        int byte = (row << 9) + (q << 3);
        byte ^= (row & 7) << 4;
        *(ushort4*)((char*)As + byte) = u;
    }
    __syncthreads();

    f32x4 acc[4][4] = {};
    #pragma unroll
    for (int kk = 0; kk < 8; ++kk) {
        fragA a[4];
        #pragma unroll
        for (int m = 0; m < 4; ++m) {
            int row  = m * 16 + r16;
            int byte = (row << 9) + ((kk * 32 + g * 8) << 1);
            byte ^= (row & 7) << 4;
            a[m] = *(const fragA*)((const char*)As + byte);
        }
        #pragma unroll
        for (int m = 0; m < 4; ++m)
            #pragma unroll
            for (int nn = 0; nn < 4; ++nn)
                acc[m][nn] = __builtin_amdgcn_mfma_f32_16x16x32_bf16(
                    a[m], b[nn][kk], acc[m][nn], 0, 0, 0);
    }

    #pragma unroll
    for (int m = 0; m < 4; ++m) {
        #pragma unroll
        for (int nn = 0; nn < 4; ++nn) {
            int gcol = wave * 64 + nn * 16 + r16;
            #pragma unroll
            for (int r = 0; r < 4; ++r) {
                int grow = row0 + m * 16 + g * 4 + r;
                if (grow < M)
                    H2[(size_t)grow * (HEADS * OUTC) + gcol] = f2bf(acc[m][nn][r]);
            }
        }
    }

    {
        float as_att[4], ad_att[4];
        #pragma unroll
        for (int nn = 0; nn < 4; ++nn) {
            as_att[nn] = att_src[wave * 64 + nn * 16 + r16];
            ad_att[nn] = att_dst[wave * 64 + nn * 16 + r16];
        }
        float sv[4][4], dv[4][4];
        #pragma unroll
        for (int m = 0; m < 4; ++m)
            #pragma unroll
            for (int r = 0; r < 4; ++r) {
                float s = 0.f, d = 0.f;
                #pragma unroll
                for (int nn = 0; nn < 4; ++nn) {
                    s = fmaf(acc[m][nn][r], as_att[nn], s);
                    d = fmaf(acc[m][nn][r], ad_att[nn], d);
                }
                sv[m][r] = s; dv[m][r] = d;
            }
        #pragma unroll
        for (int off = 1; off < 16; off <<= 1) {
            #pragma unroll
            for (int m = 0; m < 4; ++m)
                #pragma unroll
                for (int r = 0; r < 4; ++r) {
                    sv[m][r] += __shfl_xor(sv[m][r], off, 64);
                    dv[m][r] += __shfl_xor(dv[m][r], off, 64);
                }
        }
        #pragma unroll
        for (int m = 0; m < 4; ++m)
            #pragma unroll
            for (int r = 0; r < 4; ++r) {
                if (r16 == m * 4 + r) {
                    int grow = row0 + m * 16 + g * 4 + r;
                    if (grow < M) {
                        a_srcO[(size_t)grow * HEADS + wave] = sv[m][r];
                        a_dstO[(size_t)grow * HEADS + wave] = dv[m][r];
                    }
                }
            }
    }
}

// ---------------- CSR build ----------------
__global__ void hist_kernel(const int* __restrict__ dst, int* __restrict__ counts, int E)
{
    int e = blockIdx.x * blockDim.x + threadIdx.x;
    if (e < E) atomicAdd(&counts[dst[e]], 1);
}

__global__ __launch_bounds__(256) void scan1_kernel(const int* __restrict__ counts,
                                                    int* __restrict__ local,
                                                    int* __restrict__ bsums, int n)
{
    __shared__ int tmp[256];
    int t = threadIdx.x;
    int i = blockIdx.x * 256 + t;
    int v = (i < n) ? counts[i] : 0;
    tmp[t] = v;
    __syncthreads();
    for (int off = 1; off < 256; off <<= 1) {
        int x = (t >= off) ? tmp[t - off] : 0;
        __syncthreads();
        tmp[t] += x;
        __syncthreads();
    }
    if (i < n) local[i] = tmp[t] - v;
    if (t == 255) bsums[blockIdx.x] = tmp[255];
}

__global__ __launch_bounds__(256) void scan3b_kernel(const int* __restrict__ local,
                                                     const int* __restrict__ bsums,
                                                     int* __restrict__ offsets,
                                                     int* __restrict__ cursor,
                                                     int n, int Etot)
{
    __shared__ int red[256];
    int t = threadIdx.x;
    int bid = blockIdx.x;
    int s = 0;
    for (int j = t; j < bid; j += 256) s += bsums[j];
    red[t] = s;
    __syncthreads();
    for (int off = 128; off > 0; off >>= 1) {
        if (t < off) red[t] += red[t + off];
        __syncthreads();
    }
    int base = red[0];
    int i = bid * 256 + t;
    if (i < n) {
        int o = local[i] + base;
        offsets[i] = o;
        cursor[i]  = o;
    }
    if (bid == 0 && t == 0) offsets[n] = Etot;
}

// ---------------- scatter: one 8B {src,dst} pair per edge ----------------
__global__ void scatter_pair_kernel(const int* __restrict__ src, const int* __restrict__ dst,
                                    int* __restrict__ cursor,
                                    int2* __restrict__ esd, int E)
{
    int e = blockIdx.x * blockDim.x + threadIdx.x;
    if (e >= E) return;
    int s = src[e], d = dst[e];
    int pos = atomicAdd(&cursor[d], 1);
    esd[pos] = make_int2(s, d);
}

// ---------------- alpha: fully coalesced pass over CSR order ----------------
__global__ __launch_bounds__(256) void alpha2_kernel(const int2* __restrict__ esd,
                                                     const float* __restrict__ a_src,
                                                     const float* __restrict__ a_dst,
                                                     int* __restrict__ esrc,
                                                     float* __restrict__ palpha,  // [4][E]
                                                     int E)
{
    int j = blockIdx.x * blockDim.x + threadIdx.x;
    if (j >= E) return;
    int2 sd = esd[j];
    float4 as = *(const float4*)(a_src + (size_t)sd.x * HEADS);
    float4 ad = *(const float4*)(a_dst + (size_t)sd.y * HEADS);
    float t, p0, p1, p2, p3;
    t = as.x + ad.x; t = t > 0.f ? t : NEG_SLOPE * t; p0 = __expf(t);
    t = as.y + ad.y; t = t > 0.f ? t : NEG_SLOPE * t; p1 = __expf(t);
    t = as.z + ad.z; t = t > 0.f ? t : NEG_SLOPE * t; p2 = __expf(t);
    t = as.w + ad.w; t = t > 0.f ? t : NEG_SLOPE * t; p3 = __expf(t);
    esrc[j] = sd.x;
    palpha[j]                   = p0;
    palpha[(size_t)E + j]       = p1;
    palpha[2 * (size_t)E + j]   = p2;
    palpha[3 * (size_t)E + j]   = p3;
}

// ---------------- fused aggregation: wave per node; lane = head*16 + cg ----------------
__global__ __launch_bounds__(256) void fused_agg_kernel(
    const unsigned short* __restrict__ h2,      // [N,256] bf16
    const float* __restrict__ a_src,            // [N,4]
    const float* __restrict__ a_dst,            // [N,4]
    const int*   __restrict__ offsets,          // [N+1]
    const int*   __restrict__ esrc,             // [E]
    const float* __restrict__ palpha,           // [4][E]
    const float* __restrict__ bias,             // [64]
    float*       __restrict__ out,              // [N,64]
    int n, int E)
{
    int i    = (int)((blockIdx.x * blockDim.x + threadIdx.x) >> 6);
    int lane = threadIdx.x & 63;
    if (i >= n) return;
    const int h  = lane >> 4;
    const int cg = lane & 15;

    float acc0, acc1, acc2, acc3, l;
    {   // self-loop
        float as = a_src[(size_t)i * HEADS + h];
        float ad = a_dst[(size_t)i * HEADS + h];
        float e = as + ad; e = e > 0.f ? e : NEG_SLOPE * e;
        float p = __expf(e);
        ushort4 v = *(const ushort4*)(h2 + (size_t)i * 256 + lane * 4);
        l = p;
        acc0 = p * bf2f(v.x);
        acc1 = p * bf2f(v.y);
        acc2 = p * bf2f(v.z);
        acc3 = p * bf2f(v.w);
    }

    const float* pa = palpha + (size_t)h * E;
    int beg = offsets[i], end = offsets[i + 1];
    int j = beg;
    for (; j + 3 < end; j += 4) {
        int s0 = esrc[j];
        int s1 = esrc[j + 1];
        int s2 = esrc[j + 2];
        int s3 = esrc[j + 3];
        float p0 = pa[j];
        float p1 = pa[j + 1];
        float p2 = pa[j + 2];
        float p3 = pa[j + 3];
        ushort4 v0 = *(const ushort4*)(h2 + (size_t)s0 * 256 + lane * 4);
        ushort4 v1 = *(const ushort4*)(h2 + (size_t)s1 * 256 + lane * 4);
        ushort4 v2 = *(const ushort4*)(h2 + (size_t)s2 * 256 + lane * 4);
        ushort4 v3 = *(const ushort4*)(h2 + (size_t)s3 * 256 + lane * 4);
        l += (p0 + p1) + (p2 + p3);
        acc0 = fmaf(p0, bf2f(v0.x), acc0);
        acc1 = fmaf(p0, bf2f(v0.y), acc1);
        acc2 = fmaf(p0, bf2f(v0.z), acc2);
        acc3 = fmaf(p0, bf2f(v0.w), acc3);
        acc0 = fmaf(p1, bf2f(v1.x), acc0);
        acc1 = fmaf(p1, bf2f(v1.y), acc1);
        acc2 = fmaf(p1, bf2f(v1.z), acc2);
        acc3 = fmaf(p1, bf2f(v1.w), acc3);
        acc0 = fmaf(p2, bf2f(v2.x), acc0);
        acc1 = fmaf(p2, bf2f(v2.y), acc1);
        acc2 = fmaf(p2, bf2f(v2.z), acc2);
        acc3 = fmaf(p2, bf2f(v2.w), acc3);
        acc0 = fmaf(p3, bf2f(v3.x), acc0);
        acc1 = fmaf(p3, bf2f(v3.y), acc1);
        acc2 = fmaf(p3, bf2f(v3.z), acc2);
        acc3 = fmaf(p3, bf2f(v3.w), acc3);
    }
    for (; j < end; ++j) {
        int s0 = esrc[j];
        float p0 = pa[j];
        ushort4 v0 = *(const ushort4*)(h2 + (size_t)s0 * 256 + lane * 4);
        l += p0;
        acc0 = fmaf(p0, bf2f(v0.x), acc0);
        acc1 = fmaf(p0, bf2f(v0.y), acc1);
        acc2 = fmaf(p0, bf2f(v0.z), acc2);
        acc3 = fmaf(p0, bf2f(v0.w), acc3);
    }

    float inv = 1.f / (l + 1e-16f);
    float r0 = acc0 * inv, r1 = acc1 * inv, r2 = acc2 * inv, r3 = acc3 * inv;

    r0 += __shfl_xor(r0, 16, 64); r0 += __shfl_xor(r0, 32, 64);
    r1 += __shfl_xor(r1, 16, 64); r1 += __shfl_xor(r1, 32, 64);
    r2 += __shfl_xor(r2, 16, 64); r2 += __shfl_xor(r2, 32, 64);
    r3 += __shfl_xor(r3, 16, 64); r3 += __shfl_xor(r3, 32, 64);

    if (lane < 16) {
        float4 b4 = *(const float4*)(bias + cg * 4);
        float4 o;
        o.x = 0.25f * r0 + b4.x;
        o.y = 0.25f * r1 + b4.y;
        o.z = 0.25f * r2 + b4.z;
        o.w = 0.25f * r3 + b4.w;
        *(float4*)(out + (size_t)i * OUTC + cg * 4) = o;
    }
}

extern "C" void kernel_launch(void* const* d_in, const int* in_sizes, int n_in,
                              void* d_out, int out_size, void* d_ws, size_t ws_size,
                              hipStream_t stream)
{
    (void)n_in; (void)out_size; (void)ws_size;
    const float* x       = (const float*)d_in[0];
    const int*   edge    = (const int*)d_in[1];
    const float* W       = (const float*)d_in[2];
    const float* att_src = (const float*)d_in[3];
    const float* att_dst = (const float*)d_in[4];
    const float* bias    = (const float*)d_in[5];
    float* out = (float*)d_out;

    const int N = in_sizes[0] / INC;
    const int E = in_sizes[1] / 2;
    const int* srcA = edge;
    const int* dstA = edge + E;

    char* ws = (char*)d_ws;
    unsigned short* h2 = (unsigned short*)ws; ws += (size_t)N * (HEADS * OUTC) * sizeof(unsigned short);
    unsigned short* Wt = (unsigned short*)ws; ws += (size_t)256 * 256 * sizeof(unsigned short);
    float* a_src  = (float*)ws; ws += (size_t)N * HEADS * sizeof(float);
    float* a_dst  = (float*)ws; ws += (size_t)N * HEADS * sizeof(float);
    int* counts   = (int*)ws;   ws += (size_t)N * sizeof(int);
    int* offsets  = (int*)ws;   ws += (size_t)(N + 1) * sizeof(int) + 12;
    int* cursor   = (int*)ws;   ws += (size_t)N * sizeof(int);
    int* local    = (int*)ws;   ws += (size_t)N * sizeof(int);
    int* bsums    = (int*)ws;   ws += (size_t)1024 * sizeof(int);
    int2* esd     = (int2*)ws;  ws += (size_t)E * sizeof(int2);
    int* esrc     = (int*)ws;   ws += (size_t)E * sizeof(int);
    float* palpha = (float*)ws; ws += (size_t)4 * E * sizeof(float);

    const int nb = (N + 255) / 256;

    wt_zero_kernel<<<256, 256, 0, stream>>>(W, Wt, counts, N);

    hist_kernel<<<(E + 255) / 256, 256, 0, stream>>>(dstA, counts, E);

    gemm_att_mfma<<<(N + 63) / 64, 256, 0, stream>>>(x, Wt, att_src, att_dst,
                                                     h2, a_src, a_dst, N);

    scan1_kernel<<<nb, 256, 0, stream>>>(counts, local, bsums, N);
    scan3b_kernel<<<nb, 256, 0, stream>>>(local, bsums, offsets, cursor, N, E);

    scatter_pair_kernel<<<(E + 255) / 256, 256, 0, stream>>>(srcA, dstA, cursor, esd, E);

    alpha2_kernel<<<(E + 255) / 256, 256, 0, stream>>>(esd, a_src, a_dst, esrc, palpha, E);

    fused_agg_kernel<<<(N + 3) / 4, 256, 0, stream>>>(h2, a_src, a_dst, offsets, esrc,
                                                      palpha, bias, out, N, E);
}

// Round 8
// 135.012 us; speedup vs baseline: 1.6058x; 1.5557x over previous
//
#include <hip/hip_runtime.h>
#include <hip/hip_bf16.h>

#define INC   256
#define HEADS 4
#define OUTC  64
#define NEG_SLOPE 0.2f
#define CAP   5120      // per-bucket edge capacity (lambda=4096, +16 sigma)
#define EPB_A 4096      // edges per pass-A block

typedef __attribute__((ext_vector_type(8))) short  fragA;  // 8 bf16 in 4 VGPRs
typedef __attribute__((ext_vector_type(4))) float  f32x4;

__device__ __forceinline__ float bf2f(unsigned short u) {
    union { unsigned int i; float f; } v; v.i = ((unsigned int)u) << 16; return v.f;
}
__device__ __forceinline__ unsigned short f2bf(float x) {
    __hip_bfloat16 b = __float2bfloat16(x);
    return *reinterpret_cast<unsigned short*>(&b);
}

// ---------------- Wt = bf16(W^T) [256 n][256 k]; also zero bucket tails ----------------
__global__ __launch_bounds__(256) void wt_zero_kernel(const float* __restrict__ W,
                                                      unsigned short* __restrict__ Wt,
                                                      int* __restrict__ btail, int nbuck)
{
    int idx = blockIdx.x * 256 + threadIdx.x;   // 0..65535
    int k = idx >> 8, c = idx & 255;
    Wt[c * 256 + k] = f2bf(W[k * 256 + c]);
    if (idx < nbuck) btail[idx] = 0;
}

// ---------------- heterogeneous: pass-A bucket scatter (blocks < nbA) + GEMM ----------------
// GEMM: h2 = bf16(x @ W); a_src/a_dst from f32 acc. 4 waves, wave = head/col-slice.
__global__ __launch_bounds__(256, 2) void gemm_passA(
    const float* __restrict__ A,            // [M,256] f32
    const unsigned short* __restrict__ Wt,  // [256 n][256 k] bf16
    const float* __restrict__ att_src,      // [4,64]
    const float* __restrict__ att_dst,      // [4,64]
    unsigned short* __restrict__ H2,        // [M,256] bf16
    float* __restrict__ a_srcO,             // [M,4]
    float* __restrict__ a_dstO,             // [M,4]
    int M,
    const int* __restrict__ src, const int* __restrict__ dst,
    int* __restrict__ btail,                // [nbuck]
    int2* __restrict__ bucketbuf,           // [nbuck*CAP]
    int E, int nbA)
{
    __shared__ __align__(16) unsigned short As[64 * 256];   // 32 KB (pass A reuses)
    const int tid = threadIdx.x;

    if ((int)blockIdx.x < nbA) {
        // ---------------- pass A: bin edges by dst>>8 ----------------
        char* sm = (char*)As;
        int* lhist = (int*)sm;            // 256 ints
        int* lrankc = (int*)(sm + 1024);  // 256 ints
        int* gbase  = (int*)(sm + 2048);  // 256 ints
        lhist[tid] = 0; lrankc[tid] = 0;
        __syncthreads();
        int e0 = blockIdx.x * EPB_A;
        int e1 = e0 + EPB_A; if (e1 > E) e1 = E;
        for (int e = e0 + tid; e < e1; e += 256)
            atomicAdd(&lhist[dst[e] >> 8], 1);
        __syncthreads();
        {
            int c = lhist[tid];
            gbase[tid] = (c > 0) ? atomicAdd(&btail[tid], c) : 0;
        }
        __syncthreads();
        for (int e = e0 + tid; e < e1; e += 256) {
            int s = src[e], d = dst[e];
            int b = d >> 8;
            int r = atomicAdd(&lrankc[b], 1);
            bucketbuf[(size_t)b * CAP + gbase[b] + r] = make_int2(s, d);
        }
        return;
    }

    // ---------------- GEMM blocks ----------------
    const int lane = tid & 63;
    const int wave = tid >> 6;
    const int row0 = ((int)blockIdx.x - nbA) * 64;
    const int g   = lane >> 4;
    const int r16 = lane & 15;

    fragA b[4][8];
    {
        const unsigned short* wp = Wt + (size_t)(wave * 64) * 256;
        #pragma unroll
        for (int nn = 0; nn < 4; ++nn)
            #pragma unroll
            for (int kk = 0; kk < 8; ++kk)
                b[nn][kk] = *(const fragA*)(wp + (size_t)(nn * 16 + r16) * 256 + kk * 32 + g * 8);
    }

    #pragma unroll
    for (int i = 0; i < 16; ++i) {
        int f   = i * 256 + tid;
        int row = f >> 6;
        int q   = f & 63;
        int gr  = row0 + row;
        float4 v = (gr < M) ? *(const float4*)(A + (size_t)gr * INC + q * 4)
                            : make_float4(0.f, 0.f, 0.f, 0.f);
        ushort4 u;
        u.x = f2bf(v.x); u.y = f2bf(v.y); u.z = f2bf(v.z); u.w = f2bf(v.w);
        int byte = (row << 9) + (q << 3);
        byte ^= (row & 7) << 4;
        *(ushort4*)((char*)As + byte) = u;
    }
    __syncthreads();

    f32x4 acc[4][4] = {};
    #pragma unroll
    for (int kk = 0; kk < 8; ++kk) {
        fragA a[4];
        #pragma unroll
        for (int m = 0; m < 4; ++m) {
            int row  = m * 16 + r16;
            int byte = (row << 9) + ((kk * 32 + g * 8) << 1);
            byte ^= (row & 7) << 4;
            a[m] = *(const fragA*)((const char*)As + byte);
        }
        #pragma unroll
        for (int m = 0; m < 4; ++m)
            #pragma unroll
            for (int nn = 0; nn < 4; ++nn)
                acc[m][nn] = __builtin_amdgcn_mfma_f32_16x16x32_bf16(
                    a[m], b[nn][kk], acc[m][nn], 0, 0, 0);
    }

    #pragma unroll
    for (int m = 0; m < 4; ++m) {
        #pragma unroll
        for (int nn = 0; nn < 4; ++nn) {
            int gcol = wave * 64 + nn * 16 + r16;
            #pragma unroll
            for (int r = 0; r < 4; ++r) {
                int grow = row0 + m * 16 + g * 4 + r;
                if (grow < M)
                    H2[(size_t)grow * (HEADS * OUTC) + gcol] = f2bf(acc[m][nn][r]);
            }
        }
    }

    {
        float as_att[4], ad_att[4];
        #pragma unroll
        for (int nn = 0; nn < 4; ++nn) {
            as_att[nn] = att_src[wave * 64 + nn * 16 + r16];
            ad_att[nn] = att_dst[wave * 64 + nn * 16 + r16];
        }
        float sv[4][4], dv[4][4];
        #pragma unroll
        for (int m = 0; m < 4; ++m)
            #pragma unroll
            for (int r = 0; r < 4; ++r) {
                float s = 0.f, d = 0.f;
                #pragma unroll
                for (int nn = 0; nn < 4; ++nn) {
                    s = fmaf(acc[m][nn][r], as_att[nn], s);
                    d = fmaf(acc[m][nn][r], ad_att[nn], d);
                }
                sv[m][r] = s; dv[m][r] = d;
            }
        #pragma unroll
        for (int off = 1; off < 16; off <<= 1) {
            #pragma unroll
            for (int m = 0; m < 4; ++m)
                #pragma unroll
                for (int r = 0; r < 4; ++r) {
                    sv[m][r] += __shfl_xor(sv[m][r], off, 64);
                    dv[m][r] += __shfl_xor(dv[m][r], off, 64);
                }
        }
        #pragma unroll
        for (int m = 0; m < 4; ++m)
            #pragma unroll
            for (int r = 0; r < 4; ++r) {
                if (r16 == m * 4 + r) {
                    int grow = row0 + m * 16 + g * 4 + r;
                    if (grow < M) {
                        a_srcO[(size_t)grow * HEADS + wave] = sv[m][r];
                        a_dstO[(size_t)grow * HEADS + wave] = dv[m][r];
                    }
                }
            }
    }
}

// ---------------- pass B: in-bucket counting sort -> CSR esd + offsets ----------------
__global__ __launch_bounds__(256) void passB_kernel(const int2* __restrict__ bucketbuf,
                                                    const int* __restrict__ btail,
                                                    int* __restrict__ offsets,
                                                    int2* __restrict__ esd,
                                                    int N, int E)
{
    __shared__ int lcnt[256];
    __shared__ int red[256];
    __shared__ unsigned short lrank[CAP];
    const int b = blockIdx.x, t = threadIdx.x;

    // global base = sum of preceding bucket totals
    int s0 = 0;
    for (int j = t; j < b; j += 256) s0 += btail[j];
    red[t] = s0;
    __syncthreads();
    for (int off = 128; off > 0; off >>= 1) {
        if (t < off) red[t] += red[t + off];
        __syncthreads();
    }
    const int baseg = red[0];
    const int cnt = btail[b];
    __syncthreads();

    lcnt[t] = 0;
    __syncthreads();
    const int2* bb = bucketbuf + (size_t)b * CAP;
    for (int i = t; i < cnt; i += 256)
        lrank[i] = (unsigned short)atomicAdd(&lcnt[bb[i].y & 255], 1);
    __syncthreads();

    // exclusive scan of lcnt
    int v = lcnt[t];
    red[t] = v;
    __syncthreads();
    for (int off = 1; off < 256; off <<= 1) {
        int x = (t >= off) ? red[t - off] : 0;
        __syncthreads();
        red[t] += x;
        __syncthreads();
    }
    int excl = red[t] - v;
    lcnt[t] = excl;   // reuse lcnt as exclusive offsets
    int node = b * 256 + t;
    if (node < N) offsets[node] = baseg + excl;
    if (b == 0 && t == 0) offsets[N] = E;
    __syncthreads();

    for (int i = t; i < cnt; i += 256) {
        int2 sd = bb[i];
        int slot = baseg + lcnt[sd.y & 255] + lrank[i];
        esd[slot] = sd;
    }
}

// ---------------- alpha: fully coalesced pass over CSR order ----------------
__global__ __launch_bounds__(256) void alpha2_kernel(const int2* __restrict__ esd,
                                                     const float* __restrict__ a_src,
                                                     const float* __restrict__ a_dst,
                                                     int* __restrict__ esrc,
                                                     float* __restrict__ palpha,  // [4][E]
                                                     int E)
{
    int j = blockIdx.x * blockDim.x + threadIdx.x;
    if (j >= E) return;
    int2 sd = esd[j];
    float4 as = *(const float4*)(a_src + (size_t)sd.x * HEADS);
    float4 ad = *(const float4*)(a_dst + (size_t)sd.y * HEADS);
    float t, p0, p1, p2, p3;
    t = as.x + ad.x; t = t > 0.f ? t : NEG_SLOPE * t; p0 = __expf(t);
    t = as.y + ad.y; t = t > 0.f ? t : NEG_SLOPE * t; p1 = __expf(t);
    t = as.z + ad.z; t = t > 0.f ? t : NEG_SLOPE * t; p2 = __expf(t);
    t = as.w + ad.w; t = t > 0.f ? t : NEG_SLOPE * t; p3 = __expf(t);
    esrc[j] = sd.x;
    palpha[j]                   = p0;
    palpha[(size_t)E + j]       = p1;
    palpha[2 * (size_t)E + j]   = p2;
    palpha[3 * (size_t)E + j]   = p3;
}

// ---------------- fused aggregation: wave per node; lane = head*16 + cg ----------------
__global__ __launch_bounds__(256) void fused_agg_kernel(
    const unsigned short* __restrict__ h2,      // [N,256] bf16
    const float* __restrict__ a_src,            // [N,4]
    const float* __restrict__ a_dst,            // [N,4]
    const int*   __restrict__ offsets,          // [N+1]
    const int*   __restrict__ esrc,             // [E]
    const float* __restrict__ palpha,           // [4][E]
    const float* __restrict__ bias,             // [64]
    float*       __restrict__ out,              // [N,64]
    int n, int E)
{
    int i    = (int)((blockIdx.x * blockDim.x + threadIdx.x) >> 6);
    int lane = threadIdx.x & 63;
    if (i >= n) return;
    const int h  = lane >> 4;
    const int cg = lane & 15;

    float acc0, acc1, acc2, acc3, l;
    {   // self-loop
        float as = a_src[(size_t)i * HEADS + h];
        float ad = a_dst[(size_t)i * HEADS + h];
        float e = as + ad; e = e > 0.f ? e : NEG_SLOPE * e;
        float p = __expf(e);
        ushort4 v = *(const ushort4*)(h2 + (size_t)i * 256 + lane * 4);
        l = p;
        acc0 = p * bf2f(v.x);
        acc1 = p * bf2f(v.y);
        acc2 = p * bf2f(v.z);
        acc3 = p * bf2f(v.w);
    }

    const float* pa = palpha + (size_t)h * E;
    int beg = offsets[i], end = offsets[i + 1];
    int j = beg;
    for (; j + 3 < end; j += 4) {
        int s0 = esrc[j];
        int s1 = esrc[j + 1];
        int s2 = esrc[j + 2];
        int s3 = esrc[j + 3];
        float p0 = pa[j];
        float p1 = pa[j + 1];
        float p2 = pa[j + 2];
        float p3 = pa[j + 3];
        ushort4 v0 = *(const ushort4*)(h2 + (size_t)s0 * 256 + lane * 4);
        ushort4 v1 = *(const ushort4*)(h2 + (size_t)s1 * 256 + lane * 4);
        ushort4 v2 = *(const ushort4*)(h2 + (size_t)s2 * 256 + lane * 4);
        ushort4 v3 = *(const ushort4*)(h2 + (size_t)s3 * 256 + lane * 4);
        l += (p0 + p1) + (p2 + p3);
        acc0 = fmaf(p0, bf2f(v0.x), acc0);
        acc1 = fmaf(p0, bf2f(v0.y), acc1);
        acc2 = fmaf(p0, bf2f(v0.z), acc2);
        acc3 = fmaf(p0, bf2f(v0.w), acc3);
        acc0 = fmaf(p1, bf2f(v1.x), acc0);
        acc1 = fmaf(p1, bf2f(v1.y), acc1);
        acc2 = fmaf(p1, bf2f(v1.z), acc2);
        acc3 = fmaf(p1, bf2f(v1.w), acc3);
        acc0 = fmaf(p2, bf2f(v2.x), acc0);
        acc1 = fmaf(p2, bf2f(v2.y), acc1);
        acc2 = fmaf(p2, bf2f(v2.z), acc2);
        acc3 = fmaf(p2, bf2f(v2.w), acc3);
        acc0 = fmaf(p3, bf2f(v3.x), acc0);
        acc1 = fmaf(p3, bf2f(v3.y), acc1);
        acc2 = fmaf(p3, bf2f(v3.z), acc2);
        acc3 = fmaf(p3, bf2f(v3.w), acc3);
    }
    for (; j < end; ++j) {
        int s0 = esrc[j];
        float p0 = pa[j];
        ushort4 v0 = *(const ushort4*)(h2 + (size_t)s0 * 256 + lane * 4);
        l += p0;
        acc0 = fmaf(p0, bf2f(v0.x), acc0);
        acc1 = fmaf(p0, bf2f(v0.y), acc1);
        acc2 = fmaf(p0, bf2f(v0.z), acc2);
        acc3 = fmaf(p0, bf2f(v0.w), acc3);
    }

    float inv = 1.f / (l + 1e-16f);
    float r0 = acc0 * inv, r1 = acc1 * inv, r2 = acc2 * inv, r3 = acc3 * inv;

    r0 += __shfl_xor(r0, 16, 64); r0 += __shfl_xor(r0, 32, 64);
    r1 += __shfl_xor(r1, 16, 64); r1 += __shfl_xor(r1, 32, 64);
    r2 += __shfl_xor(r2, 16, 64); r2 += __shfl_xor(r2, 32, 64);
    r3 += __shfl_xor(r3, 16, 64); r3 += __shfl_xor(r3, 32, 64);

    if (lane < 16) {
        float4 b4 = *(const float4*)(bias + cg * 4);
        float4 o;
        o.x = 0.25f * r0 + b4.x;
        o.y = 0.25f * r1 + b4.y;
        o.z = 0.25f * r2 + b4.z;
        o.w = 0.25f * r3 + b4.w;
        *(float4*)(out + (size_t)i * OUTC + cg * 4) = o;
    }
}

extern "C" void kernel_launch(void* const* d_in, const int* in_sizes, int n_in,
                              void* d_out, int out_size, void* d_ws, size_t ws_size,
                              hipStream_t stream)
{
    (void)n_in; (void)out_size; (void)ws_size;
    const float* x       = (const float*)d_in[0];
    const int*   edge    = (const int*)d_in[1];
    const float* W       = (const float*)d_in[2];
    const float* att_src = (const float*)d_in[3];
    const float* att_dst = (const float*)d_in[4];
    const float* bias    = (const float*)d_in[5];
    float* out = (float*)d_out;

    const int N = in_sizes[0] / INC;
    const int E = in_sizes[1] / 2;
    const int* srcA = edge;
    const int* dstA = edge + E;
    const int nbuck = (N + 255) / 256;          // 196
    const int nbA   = (E + EPB_A - 1) / EPB_A;  // 196

    char* ws = (char*)d_ws;
    unsigned short* h2 = (unsigned short*)ws; ws += (size_t)N * (HEADS * OUTC) * sizeof(unsigned short);
    unsigned short* Wt = (unsigned short*)ws; ws += (size_t)256 * 256 * sizeof(unsigned short);
    float* a_src  = (float*)ws; ws += (size_t)N * HEADS * sizeof(float);
    float* a_dst  = (float*)ws; ws += (size_t)N * HEADS * sizeof(float);
    int* offsets  = (int*)ws;   ws += (size_t)(N + 1) * sizeof(int) + 12;
    int* btail    = (int*)ws;   ws += (size_t)256 * sizeof(int);
    int2* bucketbuf = (int2*)ws; ws += (size_t)nbuck * CAP * sizeof(int2);
    int2* esd     = (int2*)ws;  ws += (size_t)E * sizeof(int2);
    int* esrc     = (int*)ws;   ws += (size_t)E * sizeof(int);
    float* palpha = (float*)ws; ws += (size_t)4 * E * sizeof(float);

    wt_zero_kernel<<<256, 256, 0, stream>>>(W, Wt, btail, nbuck);

    gemm_passA<<<nbA + (N + 63) / 64, 256, 0, stream>>>(
        x, Wt, att_src, att_dst, h2, a_src, a_dst, N,
        srcA, dstA, btail, bucketbuf, E, nbA);

    passB_kernel<<<nbuck, 256, 0, stream>>>(bucketbuf, btail, offsets, esd, N, E);

    alpha2_kernel<<<(E + 255) / 256, 256, 0, stream>>>(esd, a_src, a_dst, esrc, palpha, E);

    fused_agg_kernel<<<(N + 3) / 4, 256, 0, stream>>>(h2, a_src, a_dst, offsets, esrc,
                                                      palpha, bias, out, N, E);
}

// Round 9
// 129.105 us; speedup vs baseline: 1.6793x; 1.0458x over previous
//
#include <hip/hip_runtime.h>
#include <hip/hip_bf16.h>

#define INC   256
#define HEADS 4
#define OUTC  64
#define NEG_SLOPE 0.2f
#define CAP   5120      // per-bucket edge capacity (lambda=4096, +16 sigma)
#define EPB_A 4096      // edges per pass-A block

typedef __attribute__((ext_vector_type(8))) short  fragA;  // 8 bf16 in 4 VGPRs
typedef __attribute__((ext_vector_type(4))) float  f32x4;

__device__ __forceinline__ float bf2f(unsigned short u) {
    union { unsigned int i; float f; } v; v.i = ((unsigned int)u) << 16; return v.f;
}
__device__ __forceinline__ unsigned short f2bf(float x) {
    __hip_bfloat16 b = __float2bfloat16(x);
    return *reinterpret_cast<unsigned short*>(&b);
}

// ---------------- Wt = bf16(W^T) [256 n][256 k]; also zero bucket tails ----------------
__global__ __launch_bounds__(256) void wt_zero_kernel(const float* __restrict__ W,
                                                      unsigned short* __restrict__ Wt,
                                                      int* __restrict__ btail, int nbuck)
{
    int idx = blockIdx.x * 256 + threadIdx.x;   // 0..65535
    int k = idx >> 8, c = idx & 255;
    Wt[c * 256 + k] = f2bf(W[k * 256 + c]);
    if (idx < nbuck) btail[idx] = 0;
}

// ---------------- heterogeneous: pass-A bucket scatter (blocks < nbA) + GEMM ----------------
__global__ __launch_bounds__(256, 2) void gemm_passA(
    const float* __restrict__ A,            // [M,256] f32
    const unsigned short* __restrict__ Wt,  // [256 n][256 k] bf16
    const float* __restrict__ att_src,      // [4,64]
    const float* __restrict__ att_dst,      // [4,64]
    unsigned short* __restrict__ H2,        // [M,256] bf16
    float* __restrict__ a_srcO,             // [M,4]
    float* __restrict__ a_dstO,             // [M,4]
    int M,
    const int* __restrict__ src, const int* __restrict__ dst,
    int* __restrict__ btail,                // [nbuck]
    int2* __restrict__ bucketbuf,           // [nbuck*CAP]
    int E, int nbA)
{
    __shared__ __align__(16) unsigned short As[64 * 256];   // 32 KB (pass A reuses)
    const int tid = threadIdx.x;

    if ((int)blockIdx.x < nbA) {
        // ---------------- pass A: bin edges by dst>>8 ----------------
        char* sm = (char*)As;
        int* lhist = (int*)sm;            // 256 ints
        int* lrankc = (int*)(sm + 1024);  // 256 ints
        int* gbase  = (int*)(sm + 2048);  // 256 ints
        lhist[tid] = 0; lrankc[tid] = 0;
        __syncthreads();
        int e0 = blockIdx.x * EPB_A;
        int e1 = e0 + EPB_A; if (e1 > E) e1 = E;
        for (int e = e0 + tid; e < e1; e += 256)
            atomicAdd(&lhist[dst[e] >> 8], 1);
        __syncthreads();
        {
            int c = lhist[tid];
            gbase[tid] = (c > 0) ? atomicAdd(&btail[tid], c) : 0;
        }
        __syncthreads();
        for (int e = e0 + tid; e < e1; e += 256) {
            int s = src[e], d = dst[e];
            int b = d >> 8;
            int r = atomicAdd(&lrankc[b], 1);
            bucketbuf[(size_t)b * CAP + gbase[b] + r] = make_int2(s, d);
        }
        return;
    }

    // ---------------- GEMM blocks ----------------
    const int lane = tid & 63;
    const int wave = tid >> 6;
    const int row0 = ((int)blockIdx.x - nbA) * 64;
    const int g   = lane >> 4;
    const int r16 = lane & 15;

    fragA b[4][8];
    {
        const unsigned short* wp = Wt + (size_t)(wave * 64) * 256;
        #pragma unroll
        for (int nn = 0; nn < 4; ++nn)
            #pragma unroll
            for (int kk = 0; kk < 8; ++kk)
                b[nn][kk] = *(const fragA*)(wp + (size_t)(nn * 16 + r16) * 256 + kk * 32 + g * 8);
    }

    #pragma unroll
    for (int i = 0; i < 16; ++i) {
        int f   = i * 256 + tid;
        int row = f >> 6;
        int q   = f & 63;
        int gr  = row0 + row;
        float4 v = (gr < M) ? *(const float4*)(A + (size_t)gr * INC + q * 4)
                            : make_float4(0.f, 0.f, 0.f, 0.f);
        ushort4 u;
        u.x = f2bf(v.x); u.y = f2bf(v.y); u.z = f2bf(v.z); u.w = f2bf(v.w);
        int byte = (row << 9) + (q << 3);
        byte ^= (row & 7) << 4;
        *(ushort4*)((char*)As + byte) = u;
    }
    __syncthreads();

    f32x4 acc[4][4] = {};
    #pragma unroll
    for (int kk = 0; kk < 8; ++kk) {
        fragA a[4];
        #pragma unroll
        for (int m = 0; m < 4; ++m) {
            int row  = m * 16 + r16;
            int byte = (row << 9) + ((kk * 32 + g * 8) << 1);
            byte ^= (row & 7) << 4;
            a[m] = *(const fragA*)((const char*)As + byte);
        }
        #pragma unroll
        for (int m = 0; m < 4; ++m)
            #pragma unroll
            for (int nn = 0; nn < 4; ++nn)
                acc[m][nn] = __builtin_amdgcn_mfma_f32_16x16x32_bf16(
                    a[m], b[nn][kk], acc[m][nn], 0, 0, 0);
    }

    #pragma unroll
    for (int m = 0; m < 4; ++m) {
        #pragma unroll
        for (int nn = 0; nn < 4; ++nn) {
            int gcol = wave * 64 + nn * 16 + r16;
            #pragma unroll
            for (int r = 0; r < 4; ++r) {
                int grow = row0 + m * 16 + g * 4 + r;
                if (grow < M)
                    H2[(size_t)grow * (HEADS * OUTC) + gcol] = f2bf(acc[m][nn][r]);
            }
        }
    }

    {
        float as_att[4], ad_att[4];
        #pragma unroll
        for (int nn = 0; nn < 4; ++nn) {
            as_att[nn] = att_src[wave * 64 + nn * 16 + r16];
            ad_att[nn] = att_dst[wave * 64 + nn * 16 + r16];
        }
        float sv[4][4], dv[4][4];
        #pragma unroll
        for (int m = 0; m < 4; ++m)
            #pragma unroll
            for (int r = 0; r < 4; ++r) {
                float s = 0.f, d = 0.f;
                #pragma unroll
                for (int nn = 0; nn < 4; ++nn) {
                    s = fmaf(acc[m][nn][r], as_att[nn], s);
                    d = fmaf(acc[m][nn][r], ad_att[nn], d);
                }
                sv[m][r] = s; dv[m][r] = d;
            }
        #pragma unroll
        for (int off = 1; off < 16; off <<= 1) {
            #pragma unroll
            for (int m = 0; m < 4; ++m)
                #pragma unroll
                for (int r = 0; r < 4; ++r) {
                    sv[m][r] += __shfl_xor(sv[m][r], off, 64);
                    dv[m][r] += __shfl_xor(dv[m][r], off, 64);
                }
        }
        #pragma unroll
        for (int m = 0; m < 4; ++m)
            #pragma unroll
            for (int r = 0; r < 4; ++r) {
                if (r16 == m * 4 + r) {
                    int grow = row0 + m * 16 + g * 4 + r;
                    if (grow < M) {
                        a_srcO[(size_t)grow * HEADS + wave] = sv[m][r];
                        a_dstO[(size_t)grow * HEADS + wave] = dv[m][r];
                    }
                }
            }
    }
}

// ---------------- pass B: in-bucket counting sort -> CSR esrc + offsets ----------------
__global__ __launch_bounds__(256) void passB_kernel(const int2* __restrict__ bucketbuf,
                                                    const int* __restrict__ btail,
                                                    int* __restrict__ offsets,
                                                    int* __restrict__ esrc,
                                                    int N, int E)
{
    __shared__ int lcnt[256];
    __shared__ int red[256];
    __shared__ unsigned short lrank[CAP];
    const int b = blockIdx.x, t = threadIdx.x;

    int s0 = 0;
    for (int j = t; j < b; j += 256) s0 += btail[j];
    red[t] = s0;
    __syncthreads();
    for (int off = 128; off > 0; off >>= 1) {
        if (t < off) red[t] += red[t + off];
        __syncthreads();
    }
    const int baseg = red[0];
    const int cnt = btail[b];
    __syncthreads();

    lcnt[t] = 0;
    __syncthreads();
    const int2* bb = bucketbuf + (size_t)b * CAP;
    for (int i = t; i < cnt; i += 256)
        lrank[i] = (unsigned short)atomicAdd(&lcnt[bb[i].y & 255], 1);
    __syncthreads();

    int v = lcnt[t];
    red[t] = v;
    __syncthreads();
    for (int off = 1; off < 256; off <<= 1) {
        int x = (t >= off) ? red[t - off] : 0;
        __syncthreads();
        red[t] += x;
        __syncthreads();
    }
    int excl = red[t] - v;
    lcnt[t] = excl;
    int node = b * 256 + t;
    if (node < N) offsets[node] = baseg + excl;
    if (b == 0 && t == 0) offsets[N] = E;
    __syncthreads();

    for (int i = t; i < cnt; i += 256) {
        int2 sd = bb[i];
        int slot = baseg + lcnt[sd.y & 255] + lrank[i];
        esrc[slot] = sd.x;
    }
}

// ---------------- fused aggregation: wave per node; lane = head*16 + cg ----------------
// p = exp(leaky(a_src[s]+a_dst[i])) computed inline; 8-deep gather pipeline.
__global__ __launch_bounds__(256) void fused_agg_kernel(
    const unsigned short* __restrict__ h2,      // [N,256] bf16
    const float* __restrict__ a_src,            // [N,4]
    const float* __restrict__ a_dst,            // [N,4]
    const int*   __restrict__ offsets,          // [N+1]
    const int*   __restrict__ esrc,             // [E]
    const float* __restrict__ bias,             // [64]
    float*       __restrict__ out,              // [N,64]
    int n)
{
    int i    = (int)((blockIdx.x * blockDim.x + threadIdx.x) >> 6);
    int lane = threadIdx.x & 63;
    if (i >= n) return;
    const int h  = lane >> 4;
    const int cg = lane & 15;

    const float ad = a_dst[(size_t)i * HEADS + h];

    float acc0, acc1, acc2, acc3, l;
    {   // self-loop
        float as = a_src[(size_t)i * HEADS + h];
        float e = as + ad; e = e > 0.f ? e : NEG_SLOPE * e;
        float p = __expf(e);
        ushort4 v = *(const ushort4*)(h2 + (size_t)i * 256 + lane * 4);
        l = p;
        acc0 = p * bf2f(v.x);
        acc1 = p * bf2f(v.y);
        acc2 = p * bf2f(v.z);
        acc3 = p * bf2f(v.w);
    }

#define EDGE_BODY(S, AS)                                                     \
    {                                                                        \
        float e_ = (AS) + ad; e_ = e_ > 0.f ? e_ : NEG_SLOPE * e_;           \
        float p_ = __expf(e_);                                               \
        ushort4 v_ = *(const ushort4*)(h2 + (size_t)(S) * 256 + lane * 4);   \
        l += p_;                                                             \
        acc0 = fmaf(p_, bf2f(v_.x), acc0);                                   \
        acc1 = fmaf(p_, bf2f(v_.y), acc1);                                   \
        acc2 = fmaf(p_, bf2f(v_.z), acc2);                                   \
        acc3 = fmaf(p_, bf2f(v_.w), acc3);                                   \
    }

    int beg = offsets[i], end = offsets[i + 1];
    int j = beg;
    // align to 4 for int4 esrc loads
    for (; j < end && (j & 3); ++j) {
        int s = esrc[j];
        float as = a_src[(size_t)s * HEADS + h];
        EDGE_BODY(s, as);
    }
    // batches of 8: two int4 loads -> 8 a_src + 8 h2 gathers in flight
    for (; j + 7 < end; j += 8) {
        int4 ea = *(const int4*)(esrc + j);
        int4 eb = *(const int4*)(esrc + j + 4);
        float as0 = a_src[(size_t)ea.x * HEADS + h];
        float as1 = a_src[(size_t)ea.y * HEADS + h];
        float as2 = a_src[(size_t)ea.z * HEADS + h];
        float as3 = a_src[(size_t)ea.w * HEADS + h];
        float as4 = a_src[(size_t)eb.x * HEADS + h];
        float as5 = a_src[(size_t)eb.y * HEADS + h];
        float as6 = a_src[(size_t)eb.z * HEADS + h];
        float as7 = a_src[(size_t)eb.w * HEADS + h];
        ushort4 v0 = *(const ushort4*)(h2 + (size_t)ea.x * 256 + lane * 4);
        ushort4 v1 = *(const ushort4*)(h2 + (size_t)ea.y * 256 + lane * 4);
        ushort4 v2 = *(const ushort4*)(h2 + (size_t)ea.z * 256 + lane * 4);
        ushort4 v3 = *(const ushort4*)(h2 + (size_t)ea.w * 256 + lane * 4);
        ushort4 v4 = *(const ushort4*)(h2 + (size_t)eb.x * 256 + lane * 4);
        ushort4 v5 = *(const ushort4*)(h2 + (size_t)eb.y * 256 + lane * 4);
        ushort4 v6 = *(const ushort4*)(h2 + (size_t)eb.z * 256 + lane * 4);
        ushort4 v7 = *(const ushort4*)(h2 + (size_t)eb.w * 256 + lane * 4);
        float e0 = as0 + ad; e0 = e0 > 0.f ? e0 : NEG_SLOPE * e0; float p0 = __expf(e0);
        float e1 = as1 + ad; e1 = e1 > 0.f ? e1 : NEG_SLOPE * e1; float p1 = __expf(e1);
        float e2 = as2 + ad; e2 = e2 > 0.f ? e2 : NEG_SLOPE * e2; float p2 = __expf(e2);
        float e3 = as3 + ad; e3 = e3 > 0.f ? e3 : NEG_SLOPE * e3; float p3 = __expf(e3);
        float e4 = as4 + ad; e4 = e4 > 0.f ? e4 : NEG_SLOPE * e4; float p4 = __expf(e4);
        float e5 = as5 + ad; e5 = e5 > 0.f ? e5 : NEG_SLOPE * e5; float p5 = __expf(e5);
        float e6 = as6 + ad; e6 = e6 > 0.f ? e6 : NEG_SLOPE * e6; float p6 = __expf(e6);
        float e7 = as7 + ad; e7 = e7 > 0.f ? e7 : NEG_SLOPE * e7; float p7 = __expf(e7);
        l += ((p0 + p1) + (p2 + p3)) + ((p4 + p5) + (p6 + p7));
        acc0 = fmaf(p0, bf2f(v0.x), acc0);
        acc1 = fmaf(p0, bf2f(v0.y), acc1);
        acc2 = fmaf(p0, bf2f(v0.z), acc2);
        acc3 = fmaf(p0, bf2f(v0.w), acc3);
        acc0 = fmaf(p1, bf2f(v1.x), acc0);
        acc1 = fmaf(p1, bf2f(v1.y), acc1);
        acc2 = fmaf(p1, bf2f(v1.z), acc2);
        acc3 = fmaf(p1, bf2f(v1.w), acc3);
        acc0 = fmaf(p2, bf2f(v2.x), acc0);
        acc1 = fmaf(p2, bf2f(v2.y), acc1);
        acc2 = fmaf(p2, bf2f(v2.z), acc2);
        acc3 = fmaf(p2, bf2f(v2.w), acc3);
        acc0 = fmaf(p3, bf2f(v3.x), acc0);
        acc1 = fmaf(p3, bf2f(v3.y), acc1);
        acc2 = fmaf(p3, bf2f(v3.z), acc2);
        acc3 = fmaf(p3, bf2f(v3.w), acc3);
        acc0 = fmaf(p4, bf2f(v4.x), acc0);
        acc1 = fmaf(p4, bf2f(v4.y), acc1);
        acc2 = fmaf(p4, bf2f(v4.z), acc2);
        acc3 = fmaf(p4, bf2f(v4.w), acc3);
        acc0 = fmaf(p5, bf2f(v5.x), acc0);
        acc1 = fmaf(p5, bf2f(v5.y), acc1);
        acc2 = fmaf(p5, bf2f(v5.z), acc2);
        acc3 = fmaf(p5, bf2f(v5.w), acc3);
        acc0 = fmaf(p6, bf2f(v6.x), acc0);
        acc1 = fmaf(p6, bf2f(v6.y), acc1);
        acc2 = fmaf(p6, bf2f(v6.z), acc2);
        acc3 = fmaf(p6, bf2f(v6.w), acc3);
        acc0 = fmaf(p7, bf2f(v7.x), acc0);
        acc1 = fmaf(p7, bf2f(v7.y), acc1);
        acc2 = fmaf(p7, bf2f(v7.z), acc2);
        acc3 = fmaf(p7, bf2f(v7.w), acc3);
    }
    // batch of 4
    if (j + 3 < end) {
        int4 ea = *(const int4*)(esrc + j);
        float as0 = a_src[(size_t)ea.x * HEADS + h];
        float as1 = a_src[(size_t)ea.y * HEADS + h];
        float as2 = a_src[(size_t)ea.z * HEADS + h];
        float as3 = a_src[(size_t)ea.w * HEADS + h];
        EDGE_BODY(ea.x, as0);
        EDGE_BODY(ea.y, as1);
        EDGE_BODY(ea.z, as2);
        EDGE_BODY(ea.w, as3);
        j += 4;
    }
    for (; j < end; ++j) {
        int s = esrc[j];
        float as = a_src[(size_t)s * HEADS + h];
        EDGE_BODY(s, as);
    }
#undef EDGE_BODY

    float inv = 1.f / (l + 1e-16f);
    float r0 = acc0 * inv, r1 = acc1 * inv, r2 = acc2 * inv, r3 = acc3 * inv;

    r0 += __shfl_xor(r0, 16, 64); r0 += __shfl_xor(r0, 32, 64);
    r1 += __shfl_xor(r1, 16, 64); r1 += __shfl_xor(r1, 32, 64);
    r2 += __shfl_xor(r2, 16, 64); r2 += __shfl_xor(r2, 32, 64);
    r3 += __shfl_xor(r3, 16, 64); r3 += __shfl_xor(r3, 32, 64);

    if (lane < 16) {
        float4 b4 = *(const float4*)(bias + cg * 4);
        float4 o;
        o.x = 0.25f * r0 + b4.x;
        o.y = 0.25f * r1 + b4.y;
        o.z = 0.25f * r2 + b4.z;
        o.w = 0.25f * r3 + b4.w;
        *(float4*)(out + (size_t)i * OUTC + cg * 4) = o;
    }
}

extern "C" void kernel_launch(void* const* d_in, const int* in_sizes, int n_in,
                              void* d_out, int out_size, void* d_ws, size_t ws_size,
                              hipStream_t stream)
{
    (void)n_in; (void)out_size; (void)ws_size;
    const float* x       = (const float*)d_in[0];
    const int*   edge    = (const int*)d_in[1];
    const float* W       = (const float*)d_in[2];
    const float* att_src = (const float*)d_in[3];
    const float* att_dst = (const float*)d_in[4];
    const float* bias    = (const float*)d_in[5];
    float* out = (float*)d_out;

    const int N = in_sizes[0] / INC;
    const int E = in_sizes[1] / 2;
    const int* srcA = edge;
    const int* dstA = edge + E;
    const int nbuck = (N + 255) / 256;          // 196
    const int nbA   = (E + EPB_A - 1) / EPB_A;  // 196

    char* ws = (char*)d_ws;
    unsigned short* h2 = (unsigned short*)ws; ws += (size_t)N * (HEADS * OUTC) * sizeof(unsigned short);
    unsigned short* Wt = (unsigned short*)ws; ws += (size_t)256 * 256 * sizeof(unsigned short);
    float* a_src  = (float*)ws; ws += (size_t)N * HEADS * sizeof(float);
    float* a_dst  = (float*)ws; ws += (size_t)N * HEADS * sizeof(float);
    int* offsets  = (int*)ws;   ws += (size_t)(N + 1) * sizeof(int) + 12;
    int* btail    = (int*)ws;   ws += (size_t)256 * sizeof(int);
    int2* bucketbuf = (int2*)ws; ws += (size_t)nbuck * CAP * sizeof(int2);
    int* esrc     = (int*)ws;   ws += (size_t)E * sizeof(int);

    wt_zero_kernel<<<256, 256, 0, stream>>>(W, Wt, btail, nbuck);

    gemm_passA<<<nbA + (N + 63) / 64, 256, 0, stream>>>(
        x, Wt, att_src, att_dst, h2, a_src, a_dst, N,
        srcA, dstA, btail, bucketbuf, E, nbA);

    passB_kernel<<<nbuck, 256, 0, stream>>>(bucketbuf, btail, offsets, esrc, N, E);

    fused_agg_kernel<<<(N + 3) / 4, 256, 0, stream>>>(h2, a_src, a_dst, offsets, esrc,
                                                      bias, out, N);
}

// Round 10
// 128.492 us; speedup vs baseline: 1.6873x; 1.0048x over previous
//
#include <hip/hip_runtime.h>
#include <hip/hip_bf16.h>

#define INC   256
#define HEADS 4
#define OUTC  64
#define NEG_SLOPE 0.2f
#define CAP   5120      // per-bucket edge capacity (lambda=4096, +16 sigma)
#define EPB_A 4096      // edges per pass-A block

typedef __attribute__((ext_vector_type(8))) short  fragA;  // 8 bf16 in 4 VGPRs
typedef __attribute__((ext_vector_type(4))) float  f32x4;

__device__ __forceinline__ float bf2f(unsigned short u) {
    union { unsigned int i; float f; } v; v.i = ((unsigned int)u) << 16; return v.f;
}
__device__ __forceinline__ unsigned short f2bf(float x) {
    __hip_bfloat16 b = __float2bfloat16(x);
    return *reinterpret_cast<unsigned short*>(&b);
}

// ---------------- Wt = bf16(W^T) [256 n][256 k]; also zero bucket tails ----------------
__global__ __launch_bounds__(256) void wt_zero_kernel(const float* __restrict__ W,
                                                      unsigned short* __restrict__ Wt,
                                                      int* __restrict__ btail, int nbuck)
{
    int idx = blockIdx.x * 256 + threadIdx.x;   // 0..65535
    int k = idx >> 8, c = idx & 255;
    Wt[c * 256 + k] = f2bf(W[k * 256 + c]);
    if (idx < nbuck) btail[idx] = 0;
}

// ---------------- heterogeneous: pass-A bucket scatter (blocks < nbA) + GEMM ----------------
__global__ __launch_bounds__(256, 2) void gemm_passA(
    const float* __restrict__ A,            // [M,256] f32
    const unsigned short* __restrict__ Wt,  // [256 n][256 k] bf16
    const float* __restrict__ att_src,      // [4,64]
    const float* __restrict__ att_dst,      // [4,64]
    unsigned short* __restrict__ H2,        // [M,256] bf16
    float* __restrict__ a_srcO,             // [M,4]
    float* __restrict__ a_dstO,             // [M,4]
    int M,
    const int* __restrict__ src, const int* __restrict__ dst,
    int* __restrict__ btail,                // [nbuck]
    int2* __restrict__ bucketbuf,           // [nbuck*CAP]
    int E, int nbA)
{
    __shared__ __align__(16) unsigned short As[64 * 256];   // 32 KB (pass A reuses)
    const int tid = threadIdx.x;

    if ((int)blockIdx.x < nbA) {
        // ---------------- pass A: bin edges by dst>>8 ----------------
        char* sm = (char*)As;
        int* lhist = (int*)sm;            // 256 ints
        int* lrankc = (int*)(sm + 1024);  // 256 ints
        int* gbase  = (int*)(sm + 2048);  // 256 ints
        lhist[tid] = 0; lrankc[tid] = 0;
        __syncthreads();
        int e0 = blockIdx.x * EPB_A;
        int e1 = e0 + EPB_A; if (e1 > E) e1 = E;
        for (int e = e0 + tid; e < e1; e += 256)
            atomicAdd(&lhist[dst[e] >> 8], 1);
        __syncthreads();
        {
            int c = lhist[tid];
            gbase[tid] = (c > 0) ? atomicAdd(&btail[tid], c) : 0;
        }
        __syncthreads();
        for (int e = e0 + tid; e < e1; e += 256) {
            int s = src[e], d = dst[e];
            int b = d >> 8;
            int r = atomicAdd(&lrankc[b], 1);
            bucketbuf[(size_t)b * CAP + gbase[b] + r] = make_int2(s, d);
        }
        return;
    }

    // ---------------- GEMM blocks ----------------
    const int lane = tid & 63;
    const int wave = tid >> 6;
    const int row0 = ((int)blockIdx.x - nbA) * 64;
    const int g   = lane >> 4;
    const int r16 = lane & 15;

    fragA b[4][8];
    {
        const unsigned short* wp = Wt + (size_t)(wave * 64) * 256;
        #pragma unroll
        for (int nn = 0; nn < 4; ++nn)
            #pragma unroll
            for (int kk = 0; kk < 8; ++kk)
                b[nn][kk] = *(const fragA*)(wp + (size_t)(nn * 16 + r16) * 256 + kk * 32 + g * 8);
    }

    #pragma unroll
    for (int i = 0; i < 16; ++i) {
        int f   = i * 256 + tid;
        int row = f >> 6;
        int q   = f & 63;
        int gr  = row0 + row;
        float4 v = (gr < M) ? *(const float4*)(A + (size_t)gr * INC + q * 4)
                            : make_float4(0.f, 0.f, 0.f, 0.f);
        ushort4 u;
        u.x = f2bf(v.x); u.y = f2bf(v.y); u.z = f2bf(v.z); u.w = f2bf(v.w);
        int byte = (row << 9) + (q << 3);
        byte ^= (row & 7) << 4;
        *(ushort4*)((char*)As + byte) = u;
    }
    __syncthreads();

    f32x4 acc[4][4] = {};
    #pragma unroll
    for (int kk = 0; kk < 8; ++kk) {
        fragA a[4];
        #pragma unroll
        for (int m = 0; m < 4; ++m) {
            int row  = m * 16 + r16;
            int byte = (row << 9) + ((kk * 32 + g * 8) << 1);
            byte ^= (row & 7) << 4;
            a[m] = *(const fragA*)((const char*)As + byte);
        }
        #pragma unroll
        for (int m = 0; m < 4; ++m)
            #pragma unroll
            for (int nn = 0; nn < 4; ++nn)
                acc[m][nn] = __builtin_amdgcn_mfma_f32_16x16x32_bf16(
                    a[m], b[nn][kk], acc[m][nn], 0, 0, 0);
    }

    #pragma unroll
    for (int m = 0; m < 4; ++m) {
        #pragma unroll
        for (int nn = 0; nn < 4; ++nn) {
            int gcol = wave * 64 + nn * 16 + r16;
            #pragma unroll
            for (int r = 0; r < 4; ++r) {
                int grow = row0 + m * 16 + g * 4 + r;
                if (grow < M)
                    H2[(size_t)grow * (HEADS * OUTC) + gcol] = f2bf(acc[m][nn][r]);
            }
        }
    }

    {
        float as_att[4], ad_att[4];
        #pragma unroll
        for (int nn = 0; nn < 4; ++nn) {
            as_att[nn] = att_src[wave * 64 + nn * 16 + r16];
            ad_att[nn] = att_dst[wave * 64 + nn * 16 + r16];
        }
        float sv[4][4], dv[4][4];
        #pragma unroll
        for (int m = 0; m < 4; ++m)
            #pragma unroll
            for (int r = 0; r < 4; ++r) {
                float s = 0.f, d = 0.f;
                #pragma unroll
                for (int nn = 0; nn < 4; ++nn) {
                    s = fmaf(acc[m][nn][r], as_att[nn], s);
                    d = fmaf(acc[m][nn][r], ad_att[nn], d);
                }
                sv[m][r] = s; dv[m][r] = d;
            }
        #pragma unroll
        for (int off = 1; off < 16; off <<= 1) {
            #pragma unroll
            for (int m = 0; m < 4; ++m)
                #pragma unroll
                for (int r = 0; r < 4; ++r) {
                    sv[m][r] += __shfl_xor(sv[m][r], off, 64);
                    dv[m][r] += __shfl_xor(dv[m][r], off, 64);
                }
        }
        #pragma unroll
        for (int m = 0; m < 4; ++m)
            #pragma unroll
            for (int r = 0; r < 4; ++r) {
                if (r16 == m * 4 + r) {
                    int grow = row0 + m * 16 + g * 4 + r;
                    if (grow < M) {
                        a_srcO[(size_t)grow * HEADS + wave] = sv[m][r];
                        a_dstO[(size_t)grow * HEADS + wave] = dv[m][r];
                    }
                }
            }
    }
}

// ---------------- pass B: in-bucket counting sort -> CSR esrc + offsets ----------------
__global__ __launch_bounds__(256) void passB_kernel(const int2* __restrict__ bucketbuf,
                                                    const int* __restrict__ btail,
                                                    int* __restrict__ offsets,
                                                    int* __restrict__ esrc,
                                                    int N, int E)
{
    __shared__ int lcnt[256];
    __shared__ int red[256];
    __shared__ unsigned short lrank[CAP];
    const int b = blockIdx.x, t = threadIdx.x;

    int s0 = 0;
    for (int j = t; j < b; j += 256) s0 += btail[j];
    red[t] = s0;
    __syncthreads();
    for (int off = 128; off > 0; off >>= 1) {
        if (t < off) red[t] += red[t + off];
        __syncthreads();
    }
    const int baseg = red[0];
    const int cnt = btail[b];
    __syncthreads();

    lcnt[t] = 0;
    __syncthreads();
    const int2* bb = bucketbuf + (size_t)b * CAP;
    for (int i = t; i < cnt; i += 256)
        lrank[i] = (unsigned short)atomicAdd(&lcnt[bb[i].y & 255], 1);
    __syncthreads();

    int v = lcnt[t];
    red[t] = v;
    __syncthreads();
    for (int off = 1; off < 256; off <<= 1) {
        int x = (t >= off) ? red[t - off] : 0;
        __syncthreads();
        red[t] += x;
        __syncthreads();
    }
    int excl = red[t] - v;
    lcnt[t] = excl;
    int node = b * 256 + t;
    if (node < N) offsets[node] = baseg + excl;
    if (b == 0 && t == 0) offsets[N] = E;
    __syncthreads();

    for (int i = t; i < cnt; i += 256) {
        int2 sd = bb[i];
        int slot = baseg + lcnt[sd.y & 255] + lrank[i];
        esrc[slot] = sd.x;
    }
}

// ---------------- fused aggregation: 128-thread blocks (2 waves) for fine-grained
// CU refill under Poisson-degree imbalance; lane = head*16 + cg; inline exp;
// 8-deep gather pipeline (a_src issued before h2 -> exps overlap h2 returns).
__global__ __launch_bounds__(128) void fused_agg_kernel(
    const unsigned short* __restrict__ h2,      // [N,256] bf16
    const float* __restrict__ a_src,            // [N,4]
    const float* __restrict__ a_dst,            // [N,4]
    const int*   __restrict__ offsets,          // [N+1]
    const int*   __restrict__ esrc,             // [E]
    const float* __restrict__ bias,             // [64]
    float*       __restrict__ out,              // [N,64]
    int n)
{
    int i    = (int)((blockIdx.x * blockDim.x + threadIdx.x) >> 6);
    int lane = threadIdx.x & 63;
    if (i >= n) return;
    const int h  = lane >> 4;
    const int cg = lane & 15;

    const float ad = a_dst[(size_t)i * HEADS + h];

    float acc0, acc1, acc2, acc3, l;
    {   // self-loop
        float as = a_src[(size_t)i * HEADS + h];
        float e = as + ad; e = e > 0.f ? e : NEG_SLOPE * e;
        float p = __expf(e);
        ushort4 v = *(const ushort4*)(h2 + (size_t)i * 256 + lane * 4);
        l = p;
        acc0 = p * bf2f(v.x);
        acc1 = p * bf2f(v.y);
        acc2 = p * bf2f(v.z);
        acc3 = p * bf2f(v.w);
    }

#define EDGE_BODY(S, AS)                                                     \
    {                                                                        \
        float e_ = (AS) + ad; e_ = e_ > 0.f ? e_ : NEG_SLOPE * e_;           \
        float p_ = __expf(e_);                                               \
        ushort4 v_ = *(const ushort4*)(h2 + (size_t)(S) * 256 + lane * 4);   \
        l += p_;                                                             \
        acc0 = fmaf(p_, bf2f(v_.x), acc0);                                   \
        acc1 = fmaf(p_, bf2f(v_.y), acc1);                                   \
        acc2 = fmaf(p_, bf2f(v_.z), acc2);                                   \
        acc3 = fmaf(p_, bf2f(v_.w), acc3);                                   \
    }

    int beg = offsets[i], end = offsets[i + 1];
    int j = beg;
    // align to 4 for int4 esrc loads
    for (; j < end && (j & 3); ++j) {
        int s = esrc[j];
        float as = a_src[(size_t)s * HEADS + h];
        EDGE_BODY(s, as);
    }
    // batches of 8: two int4 loads -> 8 a_src + 8 h2 gathers in flight
    for (; j + 7 < end; j += 8) {
        int4 ea = *(const int4*)(esrc + j);
        int4 eb = *(const int4*)(esrc + j + 4);
        float as0 = a_src[(size_t)ea.x * HEADS + h];
        float as1 = a_src[(size_t)ea.y * HEADS + h];
        float as2 = a_src[(size_t)ea.z * HEADS + h];
        float as3 = a_src[(size_t)ea.w * HEADS + h];
        float as4 = a_src[(size_t)eb.x * HEADS + h];
        float as5 = a_src[(size_t)eb.y * HEADS + h];
        float as6 = a_src[(size_t)eb.z * HEADS + h];
        float as7 = a_src[(size_t)eb.w * HEADS + h];
        ushort4 v0 = *(const ushort4*)(h2 + (size_t)ea.x * 256 + lane * 4);
        ushort4 v1 = *(const ushort4*)(h2 + (size_t)ea.y * 256 + lane * 4);
        ushort4 v2 = *(const ushort4*)(h2 + (size_t)ea.z * 256 + lane * 4);
        ushort4 v3 = *(const ushort4*)(h2 + (size_t)ea.w * 256 + lane * 4);
        ushort4 v4 = *(const ushort4*)(h2 + (size_t)eb.x * 256 + lane * 4);
        ushort4 v5 = *(const ushort4*)(h2 + (size_t)eb.y * 256 + lane * 4);
        ushort4 v6 = *(const ushort4*)(h2 + (size_t)eb.z * 256 + lane * 4);
        ushort4 v7 = *(const ushort4*)(h2 + (size_t)eb.w * 256 + lane * 4);
        float e0 = as0 + ad; e0 = e0 > 0.f ? e0 : NEG_SLOPE * e0; float p0 = __expf(e0);
        float e1 = as1 + ad; e1 = e1 > 0.f ? e1 : NEG_SLOPE * e1; float p1 = __expf(e1);
        float e2 = as2 + ad; e2 = e2 > 0.f ? e2 : NEG_SLOPE * e2; float p2 = __expf(e2);
        float e3 = as3 + ad; e3 = e3 > 0.f ? e3 : NEG_SLOPE * e3; float p3 = __expf(e3);
        float e4 = as4 + ad; e4 = e4 > 0.f ? e4 : NEG_SLOPE * e4; float p4 = __expf(e4);
        float e5 = as5 + ad; e5 = e5 > 0.f ? e5 : NEG_SLOPE * e5; float p5 = __expf(e5);
        float e6 = as6 + ad; e6 = e6 > 0.f ? e6 : NEG_SLOPE * e6; float p6 = __expf(e6);
        float e7 = as7 + ad; e7 = e7 > 0.f ? e7 : NEG_SLOPE * e7; float p7 = __expf(e7);
        l += ((p0 + p1) + (p2 + p3)) + ((p4 + p5) + (p6 + p7));
        acc0 = fmaf(p0, bf2f(v0.x), acc0);
        acc1 = fmaf(p0, bf2f(v0.y), acc1);
        acc2 = fmaf(p0, bf2f(v0.z), acc2);
        acc3 = fmaf(p0, bf2f(v0.w), acc3);
        acc0 = fmaf(p1, bf2f(v1.x), acc0);
        acc1 = fmaf(p1, bf2f(v1.y), acc1);
        acc2 = fmaf(p1, bf2f(v1.z), acc2);
        acc3 = fmaf(p1, bf2f(v1.w), acc3);
        acc0 = fmaf(p2, bf2f(v2.x), acc0);
        acc1 = fmaf(p2, bf2f(v2.y), acc1);
        acc2 = fmaf(p2, bf2f(v2.z), acc2);
        acc3 = fmaf(p2, bf2f(v2.w), acc3);
        acc0 = fmaf(p3, bf2f(v3.x), acc0);
        acc1 = fmaf(p3, bf2f(v3.y), acc1);
        acc2 = fmaf(p3, bf2f(v3.z), acc2);
        acc3 = fmaf(p3, bf2f(v3.w), acc3);
        acc0 = fmaf(p4, bf2f(v4.x), acc0);
        acc1 = fmaf(p4, bf2f(v4.y), acc1);
        acc2 = fmaf(p4, bf2f(v4.z), acc2);
        acc3 = fmaf(p4, bf2f(v4.w), acc3);
        acc0 = fmaf(p5, bf2f(v5.x), acc0);
        acc1 = fmaf(p5, bf2f(v5.y), acc1);
        acc2 = fmaf(p5, bf2f(v5.z), acc2);
        acc3 = fmaf(p5, bf2f(v5.w), acc3);
        acc0 = fmaf(p6, bf2f(v6.x), acc0);
        acc1 = fmaf(p6, bf2f(v6.y), acc1);
        acc2 = fmaf(p6, bf2f(v6.z), acc2);
        acc3 = fmaf(p6, bf2f(v6.w), acc3);
        acc0 = fmaf(p7, bf2f(v7.x), acc0);
        acc1 = fmaf(p7, bf2f(v7.y), acc1);
        acc2 = fmaf(p7, bf2f(v7.z), acc2);
        acc3 = fmaf(p7, bf2f(v7.w), acc3);
    }
    // batch of 4
    if (j + 3 < end) {
        int4 ea = *(const int4*)(esrc + j);
        float as0 = a_src[(size_t)ea.x * HEADS + h];
        float as1 = a_src[(size_t)ea.y * HEADS + h];
        float as2 = a_src[(size_t)ea.z * HEADS + h];
        float as3 = a_src[(size_t)ea.w * HEADS + h];
        EDGE_BODY(ea.x, as0);
        EDGE_BODY(ea.y, as1);
        EDGE_BODY(ea.z, as2);
        EDGE_BODY(ea.w, as3);
        j += 4;
    }
    for (; j < end; ++j) {
        int s = esrc[j];
        float as = a_src[(size_t)s * HEADS + h];
        EDGE_BODY(s, as);
    }
#undef EDGE_BODY

    float inv = 1.f / (l + 1e-16f);
    float r0 = acc0 * inv, r1 = acc1 * inv, r2 = acc2 * inv, r3 = acc3 * inv;

    r0 += __shfl_xor(r0, 16, 64); r0 += __shfl_xor(r0, 32, 64);
    r1 += __shfl_xor(r1, 16, 64); r1 += __shfl_xor(r1, 32, 64);
    r2 += __shfl_xor(r2, 16, 64); r2 += __shfl_xor(r2, 32, 64);
    r3 += __shfl_xor(r3, 16, 64); r3 += __shfl_xor(r3, 32, 64);

    if (lane < 16) {
        float4 b4 = *(const float4*)(bias + cg * 4);
        float4 o;
        o.x = 0.25f * r0 + b4.x;
        o.y = 0.25f * r1 + b4.y;
        o.z = 0.25f * r2 + b4.z;
        o.w = 0.25f * r3 + b4.w;
        *(float4*)(out + (size_t)i * OUTC + cg * 4) = o;
    }
}

extern "C" void kernel_launch(void* const* d_in, const int* in_sizes, int n_in,
                              void* d_out, int out_size, void* d_ws, size_t ws_size,
                              hipStream_t stream)
{
    (void)n_in; (void)out_size; (void)ws_size;
    const float* x       = (const float*)d_in[0];
    const int*   edge    = (const int*)d_in[1];
    const float* W       = (const float*)d_in[2];
    const float* att_src = (const float*)d_in[3];
    const float* att_dst = (const float*)d_in[4];
    const float* bias    = (const float*)d_in[5];
    float* out = (float*)d_out;

    const int N = in_sizes[0] / INC;
    const int E = in_sizes[1] / 2;
    const int* srcA = edge;
    const int* dstA = edge + E;
    const int nbuck = (N + 255) / 256;          // 196
    const int nbA   = (E + EPB_A - 1) / EPB_A;  // 196

    char* ws = (char*)d_ws;
    unsigned short* h2 = (unsigned short*)ws; ws += (size_t)N * (HEADS * OUTC) * sizeof(unsigned short);
    unsigned short* Wt = (unsigned short*)ws; ws += (size_t)256 * 256 * sizeof(unsigned short);
    float* a_src  = (float*)ws; ws += (size_t)N * HEADS * sizeof(float);
    float* a_dst  = (float*)ws; ws += (size_t)N * HEADS * sizeof(float);
    int* offsets  = (int*)ws;   ws += (size_t)(N + 1) * sizeof(int) + 12;
    int* btail    = (int*)ws;   ws += (size_t)256 * sizeof(int);
    int2* bucketbuf = (int2*)ws; ws += (size_t)nbuck * CAP * sizeof(int2);
    int* esrc     = (int*)ws;   ws += (size_t)E * sizeof(int);

    wt_zero_kernel<<<256, 256, 0, stream>>>(W, Wt, btail, nbuck);

    gemm_passA<<<nbA + (N + 63) / 64, 256, 0, stream>>>(
        x, Wt, att_src, att_dst, h2, a_src, a_dst, N,
        srcA, dstA, btail, bucketbuf, E, nbA);

    passB_kernel<<<nbuck, 256, 0, stream>>>(bucketbuf, btail, offsets, esrc, N, E);

    fused_agg_kernel<<<(N + 1) / 2, 128, 0, stream>>>(h2, a_src, a_dst, offsets, esrc,
                                                      bias, out, N);
}